// Round 2
// baseline (224.591 us; speedup 1.0000x reference)
//
#include <hip/hip_runtime.h>
#include <math.h>

#define N_HIST 200000
#define TOPIC 128
#define HID 128
#define KSEL 50
#define EQ_CAP 4096
#define NEG_INF (-3.402823466e38f)
// log(float32(1.0 - 1e-7)) = log(0.99999988079071045)
#define LOG_DECAY (-1.1920930e-07f)

// ws layout (4-byte words):
enum { WS_HIST = 0,              // 65536 bins
       WS_CTRL = 65536,          // [0]=cntHi [1]=cntEq [2]=binB [3]=C1
       WS_ALPHA = 65552,         // N_HIST floats
       WS_HIVAL = WS_ALPHA + N_HIST,   // 64
       WS_HIIDX = WS_HIVAL + 64,       // 64
       WS_EQVAL = WS_HIIDX + 64,       // EQ_CAP
       WS_EQIDX = WS_EQVAL + EQ_CAP }; // EQ_CAP

__device__ __forceinline__ unsigned keyOf(float f) {
    unsigned u = __float_as_uint(f);
    return (u & 0x80000000u) ? ~u : (u | 0x80000000u);
}

// Kernel 1: alpha[i] = dot(vs[i], v) + 16-bit-key histogram.
// One wave = 16 rows. half = lane>>5 picks rows base..base+7 / base+8..base+15;
// lane&31 picks the float4 column. 8 independent dwordx4 loads per lane in
// flight; 8 independent 5-step shuffle chains. Grid covers all rows exactly
// once (12500 waves), no loop.
__global__ __launch_bounds__(256) void alpha_hist_kernel(
        const float* __restrict__ vs, const float* __restrict__ v,
        float* __restrict__ alpha, unsigned* __restrict__ hist) {
    const int lane = threadIdx.x & 63;
    const int wave = (blockIdx.x * blockDim.x + threadIdx.x) >> 6;
    const int half = lane >> 5;
    const int c = lane & 31;
    const int base = wave * 16 + half * 8;
    if (base >= N_HIST) return;
    const float4 vv = ((const float4*)v)[c];
    float4 a[8];
    #pragma unroll
    for (int r = 0; r < 8; ++r)
        a[r] = ((const float4*)vs)[(size_t)(base + r) * 32 + c];
    float s[8];
    #pragma unroll
    for (int r = 0; r < 8; ++r)
        s[r] = a[r].x * vv.x + a[r].y * vv.y + a[r].z * vv.z + a[r].w * vv.w;
    #pragma unroll
    for (int off = 16; off; off >>= 1) {
        #pragma unroll
        for (int r = 0; r < 8; ++r) s[r] += __shfl_xor(s[r], off);
    }
    if (c == 0) {
        #pragma unroll
        for (int r = 0; r < 8; ++r) {
            alpha[base + r] = s[r];
            atomicAdd(&hist[keyOf(s[r]) >> 16], 1u);
        }
    }
}

// Kernel 2: find bin B holding the KSEL-th largest and count C1 strictly above.
// Coalesced chunk sums: at iteration i, wave w's 64 lanes all fall in chunk
// w+4i, so a shuffle-sum + lane0 LDS store builds p[256] with coalesced loads.
__global__ __launch_bounds__(256) void scan_kernel(
        const unsigned* __restrict__ hist, unsigned* __restrict__ ctrl) {
    __shared__ unsigned p[256];
    __shared__ unsigned chunk[256];
    __shared__ int cSel;
    __shared__ unsigned cumAbove;
    const int t = threadIdx.x;
    const int wv = t >> 6, l = t & 63;
    const uint4* h4 = (const uint4*)hist;
    for (int i = 0; i < 64; ++i) {
        uint4 q = h4[t + 256 * i];
        float dummy; (void)dummy;
        unsigned s = q.x + q.y + q.z + q.w;
        #pragma unroll
        for (int off = 32; off; off >>= 1) s += __shfl_xor(s, off);
        if (l == 0) p[wv + 4 * i] = s;
    }
    __syncthreads();
    if (t == 0) {
        unsigned cum = 0; int c = 255;
        for (; c > 0; --c) {
            if (cum + p[c] >= KSEL) break;
            cum += p[c];
        }
        cSel = c; cumAbove = cum;
    }
    __syncthreads();
    chunk[t] = hist[cSel * 256 + t];
    __syncthreads();
    if (t == 0) {
        unsigned cum = cumAbove;
        int B = cSel * 256; unsigned C1v = cum;
        for (int b = 255; b >= 0; --b) {
            unsigned hb = chunk[b];
            if (cum + hb >= KSEL) { B = cSel * 256 + b; C1v = cum; break; }
            cum += hb;
        }
        ctrl[2] = (unsigned)B;
        ctrl[3] = C1v;
    }
}

// Kernel 3: gather candidates from the 800KB alpha array (L2-resident).
__global__ __launch_bounds__(256) void collect_kernel(
        const float* __restrict__ alpha, unsigned* __restrict__ ctrl,
        float* __restrict__ hiVal, unsigned* __restrict__ hiIdx,
        float* __restrict__ eqVal, unsigned* __restrict__ eqIdx) {
    const unsigned B = ctrl[2];
    int i = blockIdx.x * blockDim.x + threadIdx.x;
    const int stride = gridDim.x * blockDim.x;
    for (; i < N_HIST; i += stride) {
        float a = alpha[i];
        unsigned k16 = keyOf(a) >> 16;
        if (k16 > B) {
            unsigned pos = atomicAdd(&ctrl[0], 1u);
            if (pos < 64u) { hiVal[pos] = a; hiIdx[pos] = (unsigned)i; }
        } else if (k16 == B) {
            unsigned pos = atomicAdd(&ctrl[1], 1u);
            if (pos < (unsigned)EQ_CAP) { eqVal[pos] = a; eqIdx[pos] = (unsigned)i; }
        }
    }
}

// Kernel 4: finish top-k, decay, softmax, attn gather, score head, GRU step.
// Wave 0: selection + decay + softmax (all wave-parallel).
// Waves 1..7 concurrently: GRU matvecs with coalesced row loads + shuffle sum.
__global__ __launch_bounds__(512) void final_kernel(
        const float* __restrict__ v, const float* __restrict__ s_in,
        const float* __restrict__ t_in, const float* __restrict__ hs,
        const float* __restrict__ ts,
        const float* __restrict__ W_ih, const float* __restrict__ b_ih,
        const float* __restrict__ W_hh, const float* __restrict__ b_hh,
        const float* __restrict__ W_score, const float* __restrict__ b_score,
        const unsigned* __restrict__ ctrl,
        const float* __restrict__ hiVal, const unsigned* __restrict__ hiIdx,
        const float* __restrict__ eqVal, const unsigned* __restrict__ eqIdx,
        float* __restrict__ out) {
    __shared__ float eqV[EQ_CAP];
    __shared__ unsigned eqI[EQ_CAP];
    __shared__ float selV[KSEL];
    __shared__ unsigned selI[KSEL];
    __shared__ float w[KSEL];
    __shared__ float xv[TOPIC + 1];
    __shared__ float h0[HID];
    __shared__ float gi[3 * HID];
    __shared__ float gh[3 * HID];
    __shared__ float attnP[4][HID];
    __shared__ float red[HID];
    __shared__ int sS;

    const int t = threadIdx.x;
    const int wv = t >> 6, l = t & 63;
    const unsigned C1 = min(ctrl[3], (unsigned)KSEL);
    const unsigned ec = min(ctrl[1], (unsigned)EQ_CAP);
    int need = KSEL - (int)C1;
    if (need < 0) need = 0;
    if ((unsigned)need > ec) need = (int)ec;

    // ---- Phase A: stage pools + small vectors ----
    if (t < (int)C1) { selV[t] = hiVal[t]; selI[t] = hiIdx[t]; }
    for (int i = t; i < (int)ec; i += 512) { eqV[i] = eqVal[i]; eqI[i] = eqIdx[i]; }
    if (t < TOPIC) xv[t] = v[t];
    if (t == TOPIC) xv[TOPIC] = s_in[0];
    if (t >= 256 && t < 256 + HID) h0[t - 256] = hs[(size_t)(N_HIST - 1) * HID + (t - 256)];
    __syncthreads();

    if (wv == 0) {
        // ---- selection of `need` largest from eq pool (wave-parallel argmax) ----
        for (int j = 0; j < need; ++j) {
            float best = NEG_INF; int bi = 0;
            for (int i = l; i < (int)ec; i += 64)
                if (eqV[i] > best) { best = eqV[i]; bi = i; }
            #pragma unroll
            for (int off = 32; off; off >>= 1) {
                float ov = __shfl_xor(best, off);
                int oi = __shfl_xor(bi, off);
                if (ov > best) { best = ov; bi = oi; }
            }
            if (l == 0) {
                selV[C1 + j] = best; selI[C1 + j] = eqI[bi];
                eqV[bi] = NEG_INF;
            }
            __threadfence_block();
        }
        __threadfence_block();
        // ---- decay + softmax, wave-parallel ----
        const int S = (int)C1 + need;
        const float tt = t_in[0];
        float dv = NEG_INF; unsigned si = 0;
        if (l < S) {
            si = selI[l];
            dv = selV[l] * expf((tt - ts[si]) * LOG_DECAY);
        }
        float m = dv;
        #pragma unroll
        for (int off = 32; off; off >>= 1) m = fmaxf(m, __shfl_xor(m, off));
        float e = (l < S) ? expf(dv - m) : 0.f;
        float sum = e;
        #pragma unroll
        for (int off = 32; off; off >>= 1) sum += __shfl_xor(sum, off);
        if (l < S) w[l] = e / sum;
        if (l == 0) sS = S;
    } else {
        // ---- GRU matvecs: waves 1..7 own 55 (54 for wave 7) outputs each ----
        const int nout = (wv == 7) ? 54 : 55;
        const int obase = (wv - 1) * 55;
        const float xa = xv[l], xb = xv[64 + l], xc = xv[TOPIC];
        const float ha = h0[2 * l], hb = h0[2 * l + 1];
        for (int i = 0; i < nout; ++i) {
            const int o = obase + i;
            const float* wi = W_ih + (size_t)o * (TOPIC + 1);
            float pi = wi[l] * xa + wi[64 + l] * xb;
            if (l == 0) pi += wi[TOPIC] * xc;
            const float2 wh = ((const float2*)(W_hh + (size_t)o * HID))[l];
            float ph = wh.x * ha + wh.y * hb;
            #pragma unroll
            for (int off = 32; off; off >>= 1) {
                pi += __shfl_xor(pi, off);
                ph += __shfl_xor(ph, off);
            }
            if (l == 0) {
                gi[o] = pi + b_ih[o];
                gh[o] = ph + b_hh[o];
            }
        }
    }
    __syncthreads();

    // ---- attn partials: 4-way split over k, coalesced hs rows ----
    {
        const int g = t >> 7, col = t & 127;
        float acc = 0.f;
        const int S = sS;
        for (int k = g; k < S; k += 4)
            acc += w[k] * hs[(size_t)selI[k] * HID + col];
        attnP[g][col] = acc;
    }
    __syncthreads();

    if (t < HID) {
        const float ah = attnP[0][t] + attnP[1][t] + attnP[2][t] + attnP[3][t];
        red[t] = xv[t] * W_score[t] + ah * W_score[HID + t];
        // GRU gates
        const float r = 1.f / (1.f + expf(-(gi[t] + gh[t])));
        const float z = 1.f / (1.f + expf(-(gi[HID + t] + gh[HID + t])));
        const float n = tanhf(gi[2 * HID + t] + r * gh[2 * HID + t]);
        out[1 + t] = (1.f - z) * n + z * h0[t];
    }
    __syncthreads();

    if (t < 64) {
        float sv = red[t] + red[64 + t];
        #pragma unroll
        for (int off = 32; off; off >>= 1) sv += __shfl_xor(sv, off);
        if (t == 0) out[0] = sv + b_score[0];
    }
}

extern "C" void kernel_launch(void* const* d_in, const int* in_sizes, int n_in,
                              void* d_out, int out_size, void* d_ws, size_t ws_size,
                              hipStream_t stream) {
    const float* v       = (const float*)d_in[0];
    const float* s_in    = (const float*)d_in[1];
    const float* t_in    = (const float*)d_in[2];
    const float* vs      = (const float*)d_in[3];
    const float* hs      = (const float*)d_in[4];
    const float* ts      = (const float*)d_in[5];
    const float* W_ih    = (const float*)d_in[6];
    const float* b_ih    = (const float*)d_in[7];
    const float* W_hh    = (const float*)d_in[8];
    const float* b_hh    = (const float*)d_in[9];
    const float* W_score = (const float*)d_in[10];
    const float* b_score = (const float*)d_in[11];
    float* out = (float*)d_out;

    unsigned* ws  = (unsigned*)d_ws;
    unsigned* hist = ws + WS_HIST;
    unsigned* ctrl = ws + WS_CTRL;
    float*    alpha = (float*)(ws + WS_ALPHA);
    float*    hiVal = (float*)(ws + WS_HIVAL);
    unsigned* hiIdx = ws + WS_HIIDX;
    float*    eqVal = (float*)(ws + WS_EQVAL);
    unsigned* eqIdx = ws + WS_EQIDX;

    // zero hist + ctrl (contiguous region)
    hipMemsetAsync(d_ws, 0, (size_t)(WS_ALPHA) * 4, stream);

    // 12500 waves = 200000 rows / 16 rows-per-wave; 4 waves/block -> 3125 blocks
    alpha_hist_kernel<<<3125, 256, 0, stream>>>(vs, v, alpha, hist);
    scan_kernel<<<1, 256, 0, stream>>>(hist, ctrl);
    collect_kernel<<<256, 256, 0, stream>>>(alpha, ctrl, hiVal, hiIdx, eqVal, eqIdx);
    final_kernel<<<1, 512, 0, stream>>>(v, s_in, t_in, hs, ts,
                                        W_ih, b_ih, W_hh, b_hh, W_score, b_score,
                                        ctrl, hiVal, hiIdx, eqVal, eqIdx, out);
}

// Round 3
// 111.831 us; speedup vs baseline: 2.0083x; 2.0083x over previous
//
#include <hip/hip_runtime.h>
#include <math.h>

#define N_HIST 200000
#define TOPIC 128
#define HID 128
#define KSEL 50
#define NBINS 16384          // 14-bit order-key bins
#define NCOPY 16             // privatized histogram copies
#define NPOOL 32             // candidate sub-pools
#define POOL_CAP 256
#define NEG_INF (-3.402823466e38f)
// log(float32(1.0 - 1e-7)) = log(0.99999988079071045)
#define LOG_DECAY (-1.1920930e-07f)

// ws layout (4-byte words):
enum { WS_CTRL   = 0,                      // 64 words: [2]=B, [8..39]=pool counts
       WS_TOT    = 64,                     // 16384
       WS_CHUNK  = WS_TOT + NBINS,         // 256
       WS_ALPHA  = WS_CHUNK + 256,         // 200000
       WS_COPIES = WS_ALPHA + N_HIST,      // NCOPY*NBINS ushorts = 131072 words
       WS_POOLV  = WS_COPIES + (NCOPY * NBINS) / 2,  // 8192
       WS_POOLI  = WS_POOLV + NPOOL * POOL_CAP };    // 8192

__device__ __forceinline__ unsigned keyOf(float f) {
    unsigned u = __float_as_uint(f);
    return (u & 0x80000000u) ? ~u : (u | 0x80000000u);
}

// Kernel 1: alpha[i] = dot(vs[i], v). One wave = 16 rows, lane reads float4.
// No atomics — pure streaming.
__global__ __launch_bounds__(256) void alpha_kernel(
        const float* __restrict__ vs, const float* __restrict__ v,
        float* __restrict__ alpha) {
    const int lane = threadIdx.x & 63;
    const int wave = (blockIdx.x * blockDim.x + threadIdx.x) >> 6;
    const int half = lane >> 5;
    const int c = lane & 31;
    const int base = wave * 16 + half * 8;
    if (base >= N_HIST) return;
    const float4 vv = ((const float4*)v)[c];
    float4 a[8];
    #pragma unroll
    for (int r = 0; r < 8; ++r)
        a[r] = ((const float4*)vs)[(size_t)(base + r) * 32 + c];
    float s[8];
    #pragma unroll
    for (int r = 0; r < 8; ++r)
        s[r] = a[r].x * vv.x + a[r].y * vv.y + a[r].z * vv.z + a[r].w * vv.w;
    #pragma unroll
    for (int off = 16; off; off >>= 1) {
        #pragma unroll
        for (int r = 0; r < 8; ++r) s[r] += __shfl_xor(s[r], off);
    }
    if (c == 0) {
        float4* dst = (float4*)(alpha + base);
        dst[0] = make_float4(s[0], s[1], s[2], s[3]);
        dst[1] = make_float4(s[4], s[5], s[6], s[7]);
    }
}

// Kernel 2: privatized LDS histograms of the 14-bit key; no global atomics.
__global__ __launch_bounds__(1024) void hist_kernel(
        const float* __restrict__ alpha, unsigned short* __restrict__ copies) {
    __shared__ unsigned h[NBINS];
    const int t = threadIdx.x;
    for (int i = t; i < NBINS; i += 1024) h[i] = 0;
    __syncthreads();
    for (int i = blockIdx.x * 1024 + t; i < N_HIST; i += NCOPY * 1024)
        atomicAdd(&h[keyOf(alpha[i]) >> 18], 1u);
    __syncthreads();
    unsigned short* my = copies + (size_t)blockIdx.x * NBINS;
    for (int i = t; i < NBINS; i += 1024) my[i] = (unsigned short)h[i];
}

// Kernel 3: tot[b] = sum over copies; chunkTot[b>>6] via wave reduce.
__global__ __launch_bounds__(256) void merge_kernel(
        const unsigned short* __restrict__ copies,
        unsigned* __restrict__ tot, unsigned* __restrict__ chunkTot) {
    const int b = blockIdx.x * 256 + threadIdx.x;
    unsigned s = 0;
    #pragma unroll
    for (int c = 0; c < NCOPY; ++c) s += copies[(size_t)c * NBINS + b];
    tot[b] = s;
    unsigned cs = s;
    #pragma unroll
    for (int off = 32; off; off >>= 1) cs += __shfl_xor(cs, off);
    if ((threadIdx.x & 63) == 0) chunkTot[b >> 6] = cs;
}

// Kernel 4: find 14-bit bin B such that count(key > B) < KSEL <= count(key >= B).
__global__ __launch_bounds__(256) void scan_kernel(
        const unsigned* __restrict__ tot, const unsigned* __restrict__ chunkTot,
        unsigned* __restrict__ ctrl) {
    __shared__ unsigned ch[256];
    __shared__ unsigned bins[64];
    __shared__ int cSel;
    __shared__ unsigned cumA;
    const int t = threadIdx.x;
    ch[t] = chunkTot[t];
    __syncthreads();
    if (t == 0) {
        unsigned cum = 0; int c = 255;
        for (; c > 0; --c) {
            if (cum + ch[c] >= KSEL) break;
            cum += ch[c];
        }
        cSel = c; cumA = cum;
    }
    __syncthreads();
    if (t < 64) bins[t] = tot[cSel * 64 + t];
    __syncthreads();
    if (t == 0) {
        unsigned cum = cumA;
        unsigned B = cSel * 64;
        for (int b = 63; b >= 0; --b) {
            unsigned hb = bins[b];
            if (cum + hb >= KSEL) { B = cSel * 64 + b; break; }
            cum += hb;
        }
        ctrl[2] = B;
    }
}

// Kernel 5: gather all candidates (key14 >= B) into 32 privatized pools with
// wave-aggregated appends (one atomic per wave per hit-ballot).
__global__ __launch_bounds__(256) void collect_kernel(
        const float* __restrict__ alpha, unsigned* __restrict__ ctrl,
        float* __restrict__ poolV, unsigned* __restrict__ poolI) {
    const unsigned B = ctrl[2];
    const int lane = threadIdx.x & 63;
    const int pool = blockIdx.x & (NPOOL - 1);
    for (int i = blockIdx.x * 256 + threadIdx.x; i < N_HIST; i += gridDim.x * 256) {
        float a = alpha[i];
        bool cand = (keyOf(a) >> 18) >= B;
        unsigned long long m = __ballot(cand);
        if (m) {
            int leader = __ffsll((unsigned long long)m) - 1;
            unsigned base = 0;
            if (lane == leader) base = atomicAdd(&ctrl[8 + pool], (unsigned)__popcll(m));
            base = __shfl(base, leader);
            if (cand) {
                unsigned pos = base + (unsigned)__popcll(m & ((1ull << lane) - 1ull));
                if (pos < POOL_CAP) {
                    poolV[pool * POOL_CAP + pos] = a;
                    poolI[pool * POOL_CAP + pos] = (unsigned)i;
                }
            }
        }
    }
}

// Kernel 6: top-50 selection + decay + softmax (wave 0) concurrent with GRU
// matvecs (waves 1..7); then attn gather, score head, GRU gates.
__global__ __launch_bounds__(512) void final_kernel(
        const float* __restrict__ v, const float* __restrict__ s_in,
        const float* __restrict__ t_in, const float* __restrict__ hs,
        const float* __restrict__ ts,
        const float* __restrict__ W_ih, const float* __restrict__ b_ih,
        const float* __restrict__ W_hh, const float* __restrict__ b_hh,
        const float* __restrict__ W_score, const float* __restrict__ b_score,
        const unsigned* __restrict__ ctrl,
        const float* __restrict__ poolV, const unsigned* __restrict__ poolI,
        float* __restrict__ out) {
    __shared__ float candV[NPOOL * POOL_CAP];
    __shared__ unsigned candI[NPOOL * POOL_CAP];
    __shared__ int off[NPOOL + 1];
    __shared__ float selV[KSEL];
    __shared__ unsigned selI[KSEL];
    __shared__ float w[KSEL];
    __shared__ float xv[TOPIC + 1];
    __shared__ float h0[HID];
    __shared__ float gi[3 * HID];
    __shared__ float gh[3 * HID];
    __shared__ float attnP[4][HID];
    __shared__ float red[HID];

    const int t = threadIdx.x;
    const int wv = t >> 6, l = t & 63;

    if (t == 0) {
        int o = 0;
        for (int p = 0; p < NPOOL; ++p) {
            off[p] = o;
            o += (int)min(ctrl[8 + p], (unsigned)POOL_CAP);
        }
        off[NPOOL] = o;
    }
    if (t < TOPIC) xv[t] = v[t];
    if (t == TOPIC) xv[TOPIC] = s_in[0];
    if (t >= 256 && t < 256 + HID) h0[t - 256] = hs[(size_t)(N_HIST - 1) * HID + (t - 256)];
    __syncthreads();

    // compact pools into contiguous cand arrays
    for (int p = wv; p < NPOOL; p += 8) {
        const int cnt = off[p + 1] - off[p];
        for (int i = l; i < cnt; i += 64) {
            candV[off[p] + i] = poolV[p * POOL_CAP + i];
            candI[off[p] + i] = poolI[p * POOL_CAP + i];
        }
    }
    __syncthreads();

    const int Scand = off[NPOOL];
    const int S = Scand < KSEL ? Scand : KSEL;

    if (wv == 0) {
        // ---- top-S selection via repeated wave-parallel argmax ----
        for (int j = 0; j < S; ++j) {
            float best = NEG_INF; int bi = 0;
            for (int i = l; i < Scand; i += 64)
                if (candV[i] > best) { best = candV[i]; bi = i; }
            #pragma unroll
            for (int offx = 32; offx; offx >>= 1) {
                float ov = __shfl_xor(best, offx);
                int oi = __shfl_xor(bi, offx);
                if (ov > best) { best = ov; bi = oi; }
            }
            if (l == 0) {
                selV[j] = best; selI[j] = candI[bi];
                candV[bi] = NEG_INF;
            }
            __threadfence_block();
        }
        __threadfence_block();
        // ---- decay + softmax, wave-parallel ----
        const float tt = t_in[0];
        float dv = NEG_INF;
        if (l < S) dv = selV[l] * expf((tt - ts[selI[l]]) * LOG_DECAY);
        float m = dv;
        #pragma unroll
        for (int offx = 32; offx; offx >>= 1) m = fmaxf(m, __shfl_xor(m, offx));
        float e = (l < S) ? expf(dv - m) : 0.f;
        float sum = e;
        #pragma unroll
        for (int offx = 32; offx; offx >>= 1) sum += __shfl_xor(sum, offx);
        if (l < S) w[l] = e / sum;
    } else {
        // ---- GRU matvecs: waves 1..7 own 55 (54 for wave 7) outputs each ----
        const int nout = (wv == 7) ? 54 : 55;
        const int obase = (wv - 1) * 55;
        const float xa = xv[l], xb = xv[64 + l], xc = xv[TOPIC];
        const float ha = h0[2 * l], hb = h0[2 * l + 1];
        for (int i = 0; i < nout; ++i) {
            const int o = obase + i;
            const float* wi = W_ih + (size_t)o * (TOPIC + 1);
            float pi = wi[l] * xa + wi[64 + l] * xb;
            if (l == 0) pi += wi[TOPIC] * xc;
            const float2 wh = ((const float2*)(W_hh + (size_t)o * HID))[l];
            float ph = wh.x * ha + wh.y * hb;
            #pragma unroll
            for (int offx = 32; offx; offx >>= 1) {
                pi += __shfl_xor(pi, offx);
                ph += __shfl_xor(ph, offx);
            }
            if (l == 0) {
                gi[o] = pi + b_ih[o];
                gh[o] = ph + b_hh[o];
            }
        }
    }
    __syncthreads();

    // ---- attn partials: 4-way split over k, coalesced hs rows ----
    {
        const int g = t >> 7, col = t & 127;
        float acc = 0.f;
        for (int k = g; k < S; k += 4)
            acc += w[k] * hs[(size_t)selI[k] * HID + col];
        attnP[g][col] = acc;
    }
    __syncthreads();

    if (t < HID) {
        const float ah = attnP[0][t] + attnP[1][t] + attnP[2][t] + attnP[3][t];
        red[t] = xv[t] * W_score[t] + ah * W_score[HID + t];
        const float r = 1.f / (1.f + expf(-(gi[t] + gh[t])));
        const float z = 1.f / (1.f + expf(-(gi[HID + t] + gh[HID + t])));
        const float n = tanhf(gi[2 * HID + t] + r * gh[2 * HID + t]);
        out[1 + t] = (1.f - z) * n + z * h0[t];
    }
    __syncthreads();

    if (t < 64) {
        float sv = red[t] + red[64 + t];
        #pragma unroll
        for (int offx = 32; offx; offx >>= 1) sv += __shfl_xor(sv, offx);
        if (t == 0) out[0] = sv + b_score[0];
    }
}

extern "C" void kernel_launch(void* const* d_in, const int* in_sizes, int n_in,
                              void* d_out, int out_size, void* d_ws, size_t ws_size,
                              hipStream_t stream) {
    const float* v       = (const float*)d_in[0];
    const float* s_in    = (const float*)d_in[1];
    const float* t_in    = (const float*)d_in[2];
    const float* vs      = (const float*)d_in[3];
    const float* hs      = (const float*)d_in[4];
    const float* ts      = (const float*)d_in[5];
    const float* W_ih    = (const float*)d_in[6];
    const float* b_ih    = (const float*)d_in[7];
    const float* W_hh    = (const float*)d_in[8];
    const float* b_hh    = (const float*)d_in[9];
    const float* W_score = (const float*)d_in[10];
    const float* b_score = (const float*)d_in[11];
    float* out = (float*)d_out;

    unsigned* ws = (unsigned*)d_ws;
    unsigned*       ctrl     = ws + WS_CTRL;
    unsigned*       tot      = ws + WS_TOT;
    unsigned*       chunkTot = ws + WS_CHUNK;
    float*          alpha    = (float*)(ws + WS_ALPHA);
    unsigned short* copies   = (unsigned short*)(ws + WS_COPIES);
    float*          poolV    = (float*)(ws + WS_POOLV);
    unsigned*       poolI    = ws + WS_POOLI;

    // zero only ctrl (pool counters + B slot)
    hipMemsetAsync(ctrl, 0, 64 * sizeof(unsigned), stream);

    alpha_kernel<<<3125, 256, 0, stream>>>(vs, v, alpha);
    hist_kernel<<<NCOPY, 1024, 0, stream>>>(alpha, copies);
    merge_kernel<<<NBINS / 256, 256, 0, stream>>>(copies, tot, chunkTot);
    scan_kernel<<<1, 256, 0, stream>>>(tot, chunkTot, ctrl);
    collect_kernel<<<128, 256, 0, stream>>>(alpha, ctrl, poolV, poolI);
    final_kernel<<<1, 512, 0, stream>>>(v, s_in, t_in, hs, ts,
                                        W_ih, b_ih, W_hh, b_hh, W_score, b_score,
                                        ctrl, poolV, poolI, out);
}

// Round 4
// 61.424 us; speedup vs baseline: 3.6564x; 1.8206x over previous
//
#include <hip/hip_runtime.h>
#include <math.h>

#define N_HIST 200000
#define TOPIC 128
#define HID 128
#define KSEL 50
#define NBINS 16384          // 14-bit order-key bins
#define NCOPY 16             // privatized histogram copies
#define NPOOL 32             // candidate sub-pools
#define POOL_CAP 256
#define NEG_INF (-3.402823466e38f)
// log(float32(1.0 - 1e-7)) = log(0.99999988079071045)
#define LOG_DECAY (-1.1920930e-07f)

// ws layout (4-byte words):
enum { WS_CTRL   = 0,                      // 64 words: [2]=B, [8..39]=pool counts
       WS_TOT    = 64,                     // 16384
       WS_CHUNK  = WS_TOT + NBINS,         // 256
       WS_ALPHA  = WS_CHUNK + 256,         // 200000
       WS_COPIES = WS_ALPHA + N_HIST,      // NCOPY*NBINS ushorts = 131072 words
       WS_POOLV  = WS_COPIES + (NCOPY * NBINS) / 2,  // 8192
       WS_POOLI  = WS_POOLV + NPOOL * POOL_CAP,      // 8192
       WS_GI     = WS_POOLI + NPOOL * POOL_CAP,      // 384
       WS_GH     = WS_GI + 3 * HID };                // 384

__device__ __forceinline__ unsigned keyOf(float f) {
    unsigned u = __float_as_uint(f);
    return (u & 0x80000000u) ? ~u : (u | 0x80000000u);
}

// Kernel 1: alpha[i] = dot(vs[i], v). One wave = 16 rows, lane reads float4.
__global__ __launch_bounds__(256) void alpha_kernel(
        const float* __restrict__ vs, const float* __restrict__ v,
        float* __restrict__ alpha) {
    const int lane = threadIdx.x & 63;
    const int wave = (blockIdx.x * blockDim.x + threadIdx.x) >> 6;
    const int half = lane >> 5;
    const int c = lane & 31;
    const int base = wave * 16 + half * 8;
    const float4 vv = ((const float4*)v)[c];
    float4 a[8];
    #pragma unroll
    for (int r = 0; r < 8; ++r)
        a[r] = ((const float4*)vs)[(size_t)(base + r) * 32 + c];
    float s[8];
    #pragma unroll
    for (int r = 0; r < 8; ++r)
        s[r] = a[r].x * vv.x + a[r].y * vv.y + a[r].z * vv.z + a[r].w * vv.w;
    #pragma unroll
    for (int off = 16; off; off >>= 1) {
        #pragma unroll
        for (int r = 0; r < 8; ++r) s[r] += __shfl_xor(s[r], off);
    }
    if (c == 0) {
        float4* dst = (float4*)(alpha + base);
        dst[0] = make_float4(s[0], s[1], s[2], s[3]);
        dst[1] = make_float4(s[4], s[5], s[6], s[7]);
    }
}

// Kernel 2: privatized LDS histograms of the 14-bit key; no global atomics.
__global__ __launch_bounds__(1024) void hist_kernel(
        const float* __restrict__ alpha, unsigned short* __restrict__ copies) {
    __shared__ unsigned h[NBINS];
    const int t = threadIdx.x;
    for (int i = t; i < NBINS; i += 1024) h[i] = 0;
    __syncthreads();
    for (int i = blockIdx.x * 1024 + t; i < N_HIST; i += NCOPY * 1024)
        atomicAdd(&h[keyOf(alpha[i]) >> 18], 1u);
    __syncthreads();
    unsigned short* my = copies + (size_t)blockIdx.x * NBINS;
    for (int i = t; i < NBINS; i += 1024) my[i] = (unsigned short)h[i];
}

// Kernel 3: tot[b] = sum over copies; chunkTot[b>>6] via wave reduce.
__global__ __launch_bounds__(256) void merge_kernel(
        const unsigned short* __restrict__ copies,
        unsigned* __restrict__ tot, unsigned* __restrict__ chunkTot) {
    const int b = blockIdx.x * 256 + threadIdx.x;
    unsigned s = 0;
    #pragma unroll
    for (int c = 0; c < NCOPY; ++c) s += copies[(size_t)c * NBINS + b];
    tot[b] = s;
    unsigned cs = s;
    #pragma unroll
    for (int off = 32; off; off >>= 1) cs += __shfl_xor(cs, off);
    if ((threadIdx.x & 63) == 0) chunkTot[b >> 6] = cs;
}

// Kernel 4: find bin B (count(key > B) < KSEL <= count(key >= B)).
// Only LDS-resident serial scans; two global-load latencies total.
__global__ __launch_bounds__(256) void scan_kernel(
        const unsigned* __restrict__ tot, const unsigned* __restrict__ chunkTot,
        unsigned* __restrict__ ctrl) {
    __shared__ unsigned ch[256];
    __shared__ unsigned bins[64];
    __shared__ int cSel;
    __shared__ unsigned cumA;
    const int t = threadIdx.x;
    ch[t] = chunkTot[t];
    __syncthreads();
    if (t == 0) {
        unsigned cum = 0; int c = 255;
        for (; c > 0; --c) {
            if (cum + ch[c] >= KSEL) break;
            cum += ch[c];
        }
        cSel = c; cumA = cum;
    }
    __syncthreads();
    if (t < 64) bins[t] = tot[cSel * 64 + t];
    __syncthreads();
    if (t == 0) {
        unsigned cum = cumA;
        unsigned B = cSel * 64;
        for (int b = 63; b >= 0; --b) {
            unsigned hb = bins[b];
            if (cum + hb >= KSEL) { B = cSel * 64 + b; break; }
            cum += hb;
        }
        ctrl[2] = B;
    }
}

// Kernel 5: gather candidates (key14 >= B) into 32 pools, wave-aggregated appends.
__global__ __launch_bounds__(256) void collect_kernel(
        const float* __restrict__ alpha, unsigned* __restrict__ ctrl,
        float* __restrict__ poolV, unsigned* __restrict__ poolI) {
    const unsigned B = ctrl[2];
    const int lane = threadIdx.x & 63;
    const int pool = blockIdx.x & (NPOOL - 1);
    for (int i = blockIdx.x * 256 + threadIdx.x; i < N_HIST; i += gridDim.x * 256) {
        float a = alpha[i];
        bool cand = (keyOf(a) >> 18) >= B;
        unsigned long long m = __ballot(cand);
        if (m) {
            int leader = __ffsll((unsigned long long)m) - 1;
            unsigned base = 0;
            if (lane == leader) base = atomicAdd(&ctrl[8 + pool], (unsigned)__popcll(m));
            base = __shfl(base, leader);
            if (cand) {
                unsigned pos = base + (unsigned)__popcll(m & ((1ull << lane) - 1ull));
                if (pos < POOL_CAP) {
                    poolV[pool * POOL_CAP + pos] = a;
                    poolI[pool * POOL_CAP + pos] = (unsigned)i;
                }
            }
        }
    }
}

// Kernel 6: GRU matvecs, one wave per output (384 waves across 96 blocks).
// Single 12-deep shuffle chain per output, all in parallel across CUs.
__global__ __launch_bounds__(256) void gru_kernel(
        const float* __restrict__ v, const float* __restrict__ s_in,
        const float* __restrict__ hs,
        const float* __restrict__ W_ih, const float* __restrict__ b_ih,
        const float* __restrict__ W_hh, const float* __restrict__ b_hh,
        float* __restrict__ gi, float* __restrict__ gh) {
    const int o = (blockIdx.x << 2) | (threadIdx.x >> 6);
    const int l = threadIdx.x & 63;
    const float* wi = W_ih + (size_t)o * (TOPIC + 1);
    float pi = wi[l] * v[l] + wi[64 + l] * v[64 + l];
    if (l == 0) pi += wi[TOPIC] * s_in[0];
    const float2 wh = ((const float2*)(W_hh + (size_t)o * HID))[l];
    const float2 hh = ((const float2*)(hs + (size_t)(N_HIST - 1) * HID))[l];
    float ph = wh.x * hh.x + wh.y * hh.y;
    #pragma unroll
    for (int off = 32; off; off >>= 1) {
        pi += __shfl_xor(pi, off);
        ph += __shfl_xor(ph, off);
    }
    if (l == 0) {
        gi[o] = pi + b_ih[o];
        gh[o] = ph + b_hh[o];
    }
}

// Kernel 7: rank-based top-50 + decay + softmax + attn + score + GRU gates.
// No argmax loop, no long shuffle chains.
__global__ __launch_bounds__(512) void final_kernel(
        const float* __restrict__ v, const float* __restrict__ t_in,
        const float* __restrict__ hs, const float* __restrict__ ts,
        const float* __restrict__ W_score, const float* __restrict__ b_score,
        const unsigned* __restrict__ ctrl,
        const float* __restrict__ poolV, const unsigned* __restrict__ poolI,
        const float* __restrict__ giW, const float* __restrict__ ghW,
        float* __restrict__ out) {
    __shared__ float candV[NPOOL * POOL_CAP];
    __shared__ unsigned candI[NPOOL * POOL_CAP];
    __shared__ unsigned pc[NPOOL];
    __shared__ int off[NPOOL + 1];
    __shared__ float selV[KSEL];
    __shared__ unsigned selI[KSEL];
    __shared__ float selD[KSEL];
    __shared__ float wtmp[KSEL];
    __shared__ float w[KSEL];
    __shared__ float xv[TOPIC];
    __shared__ float h0[HID];
    __shared__ float attnP[4][HID];
    __shared__ float red[HID];

    const int t = threadIdx.x;
    const int wv = t >> 6, l = t & 63;

    if (t < NPOOL) pc[t] = min(ctrl[8 + t], (unsigned)POOL_CAP);
    if (t >= 128 && t < 256) xv[t - 128] = v[t - 128];
    if (t >= 256 && t < 256 + HID) h0[t - 256] = hs[(size_t)(N_HIST - 1) * HID + (t - 256)];
    __syncthreads();
    if (t == 0) {
        int o = 0;
        for (int p = 0; p < NPOOL; ++p) { off[p] = o; o += (int)pc[p]; }
        off[NPOOL] = o;
    }
    __syncthreads();

    // compact pools into contiguous cand arrays
    for (int p = wv; p < NPOOL; p += 8) {
        const int cnt = off[p + 1] - off[p];
        for (int i = l; i < cnt; i += 64) {
            candV[off[p] + i] = poolV[p * POOL_CAP + i];
            candI[off[p] + i] = poolI[p * POOL_CAP + i];
        }
    }
    __syncthreads();

    const int Scand = off[NPOOL];
    const int S = Scand < KSEL ? Scand : KSEL;

    // ---- rank-based selection: one pass, broadcast LDS reads, no shuffles ----
    for (int c = t; c < Scand; c += 512) {
        const float mv = candV[c];
        const unsigned mi = candI[c];
        int r = 0;
        for (int j = 0; j < Scand; ++j) {
            const float vj = candV[j];
            const unsigned ij = candI[j];
            r += (int)((vj > mv) | ((vj == mv) & (ij < mi)));
        }
        if (r < KSEL) { selV[r] = mv; selI[r] = mi; }
    }
    __syncthreads();

    // ---- decay + softmax on wave 0: redundant all-lane serial reduce ----
    if (wv == 0) {
        const float tt = t_in[0];
        float dv = NEG_INF;
        if (l < S) {
            dv = selV[l] * expf((tt - ts[selI[l]]) * LOG_DECAY);
            selD[l] = dv;
        }
        __threadfence_block();
        float m = NEG_INF;
        for (int k = 0; k < S; ++k) m = fmaxf(m, selD[k]);
        float e = (l < S) ? expf(dv - m) : 0.f;
        if (l < S) wtmp[l] = e;
        __threadfence_block();
        float sum = 0.f;
        for (int k = 0; k < S; ++k) sum += wtmp[k];
        if (l < S) w[l] = e / sum;
    }
    __syncthreads();

    // ---- attn partials: 4-way split over k, coalesced hs rows ----
    {
        const int g = t >> 7, col = t & 127;
        float acc = 0.f;
        for (int k = g; k < S; k += 4)
            acc += w[k] * hs[(size_t)selI[k] * HID + col];
        attnP[g][col] = acc;
    }
    __syncthreads();

    if (t < HID) {
        const float ah = attnP[0][t] + attnP[1][t] + attnP[2][t] + attnP[3][t];
        red[t] = xv[t] * W_score[t] + ah * W_score[HID + t];
        // GRU gates from precomputed gi/gh
        const float r = 1.f / (1.f + expf(-(giW[t] + ghW[t])));
        const float z = 1.f / (1.f + expf(-(giW[HID + t] + ghW[HID + t])));
        const float n = tanhf(giW[2 * HID + t] + r * ghW[2 * HID + t]);
        out[1 + t] = (1.f - z) * n + z * h0[t];
    }
    __syncthreads();

    if (t < 64) {
        float sv = red[t] + red[64 + t];
        #pragma unroll
        for (int offx = 32; offx; offx >>= 1) sv += __shfl_xor(sv, offx);
        if (t == 0) out[0] = sv + b_score[0];
    }
}

extern "C" void kernel_launch(void* const* d_in, const int* in_sizes, int n_in,
                              void* d_out, int out_size, void* d_ws, size_t ws_size,
                              hipStream_t stream) {
    const float* v       = (const float*)d_in[0];
    const float* s_in    = (const float*)d_in[1];
    const float* t_in    = (const float*)d_in[2];
    const float* vs      = (const float*)d_in[3];
    const float* hs      = (const float*)d_in[4];
    const float* ts      = (const float*)d_in[5];
    const float* W_ih    = (const float*)d_in[6];
    const float* b_ih    = (const float*)d_in[7];
    const float* W_hh    = (const float*)d_in[8];
    const float* b_hh    = (const float*)d_in[9];
    const float* W_score = (const float*)d_in[10];
    const float* b_score = (const float*)d_in[11];
    float* out = (float*)d_out;

    unsigned* ws = (unsigned*)d_ws;
    unsigned*       ctrl     = ws + WS_CTRL;
    unsigned*       tot      = ws + WS_TOT;
    unsigned*       chunkTot = ws + WS_CHUNK;
    float*          alpha    = (float*)(ws + WS_ALPHA);
    unsigned short* copies   = (unsigned short*)(ws + WS_COPIES);
    float*          poolV    = (float*)(ws + WS_POOLV);
    unsigned*       poolI    = ws + WS_POOLI;
    float*          giW      = (float*)(ws + WS_GI);
    float*          ghW      = (float*)(ws + WS_GH);

    hipMemsetAsync(ctrl, 0, 64 * sizeof(unsigned), stream);

    alpha_kernel<<<3125, 256, 0, stream>>>(vs, v, alpha);
    hist_kernel<<<NCOPY, 1024, 0, stream>>>(alpha, copies);
    merge_kernel<<<NBINS / 256, 256, 0, stream>>>(copies, tot, chunkTot);
    scan_kernel<<<1, 256, 0, stream>>>(tot, chunkTot, ctrl);
    collect_kernel<<<128, 256, 0, stream>>>(alpha, ctrl, poolV, poolI);
    gru_kernel<<<96, 256, 0, stream>>>(v, s_in, hs, W_ih, b_ih, W_hh, b_hh, giW, ghW);
    final_kernel<<<1, 512, 0, stream>>>(v, t_in, hs, ts, W_score, b_score,
                                        ctrl, poolV, poolI, giW, ghW, out);
}

// Round 5
// 49.742 us; speedup vs baseline: 4.5151x; 1.2348x over previous
//
#include <hip/hip_runtime.h>
#include <math.h>

#define N_HIST 200000
#define TOPIC 128
#define HID 128
#define KSEL 50
#define NBINS 4096           // 12-bit order-key bins (sign+8exp+3mant)
#define NHISTBLK 64
#define NCOLLECT 128
#define NPOOL 32
#define POOL_CAP 256
#define NEG_INF (-3.402823466e38f)
// log(float32(1.0 - 1e-7)) = log(0.99999988079071045)
#define LOG_DECAY (-1.1920930e-07f)

// ws layout (4-byte words): ctrl+tot zeroed by alpha_kernel's first blocks.
enum { WS_CTRL  = 0,                       // 64: [8..39] pool counts
       WS_TOT   = 64,                      // 4096
       WS_ZEND  = WS_TOT + NBINS,         // 4160 = zero region end
       WS_ALPHA = WS_ZEND,                 // 200000
       WS_POOLV = WS_ALPHA + N_HIST,       // 8192
       WS_POOLI = WS_POOLV + NPOOL * POOL_CAP,  // 8192
       WS_GI    = WS_POOLI + NPOOL * POOL_CAP,  // 384
       WS_GH    = WS_GI + 3 * HID };            // 384

__device__ __forceinline__ unsigned keyOf(float f) {
    unsigned u = __float_as_uint(f);
    return (u & 0x80000000u) ? ~u : (u | 0x80000000u);
}

// Kernel 1: alpha[i] = dot(vs[i], v); first 17 blocks also zero ctrl+tot.
__global__ __launch_bounds__(256) void alpha_kernel(
        const float* __restrict__ vs, const float* __restrict__ v,
        float* __restrict__ alpha, unsigned* __restrict__ wsbase) {
    const int zi = blockIdx.x * 256 + threadIdx.x;
    if (zi < WS_ZEND) wsbase[zi] = 0;
    const int lane = threadIdx.x & 63;
    const int wave = (blockIdx.x * blockDim.x + threadIdx.x) >> 6;
    const int half = lane >> 5;
    const int c = lane & 31;
    const int base = wave * 16 + half * 8;
    const float4 vv = ((const float4*)v)[c];
    float4 a[8];
    #pragma unroll
    for (int r = 0; r < 8; ++r)
        a[r] = ((const float4*)vs)[(size_t)(base + r) * 32 + c];
    float s[8];
    #pragma unroll
    for (int r = 0; r < 8; ++r)
        s[r] = a[r].x * vv.x + a[r].y * vv.y + a[r].z * vv.z + a[r].w * vv.w;
    #pragma unroll
    for (int off = 16; off; off >>= 1) {
        #pragma unroll
        for (int r = 0; r < 8; ++r) s[r] += __shfl_xor(s[r], off);
    }
    if (c == 0) {
        float4* dst = (float4*)(alpha + base);
        dst[0] = make_float4(s[0], s[1], s[2], s[3]);
        dst[1] = make_float4(s[4], s[5], s[6], s[7]);
    }
}

// Kernel 2: 12-bit histogram. Per-block packed 2x16-bit LDS bins, then one
// global atomic per nonzero bin per block (uncontended, ~500/block).
__global__ __launch_bounds__(256) void hist_kernel(
        const float* __restrict__ alpha, unsigned* __restrict__ tot) {
    __shared__ unsigned h[NBINS / 2];
    const int t = threadIdx.x;
    #pragma unroll
    for (int i = t; i < NBINS / 2; i += 256) h[i] = 0;
    __syncthreads();
    for (int i = blockIdx.x * 256 + t; i < N_HIST; i += NHISTBLK * 256) {
        unsigned b = keyOf(alpha[i]) >> 20;
        atomicAdd(&h[b >> 1], (b & 1u) ? 65536u : 1u);
    }
    __syncthreads();
    #pragma unroll
    for (int wd = t; wd < NBINS / 2; wd += 256) {
        unsigned pk = h[wd];
        unsigned lo = pk & 0xFFFFu, hi = pk >> 16;
        if (lo) atomicAdd(&tot[2 * wd], lo);
        if (hi) atomicAdd(&tot[2 * wd + 1], hi);
    }
}

// Kernel 3 (fused): blocks 0..127 collect candidates (each block redundantly
// recomputes threshold bin B from tot); blocks 128..223 do the GRU matvecs.
__global__ __launch_bounds__(256) void mid_kernel(
        const float* __restrict__ alpha, const unsigned* __restrict__ tot,
        unsigned* __restrict__ ctrl,
        float* __restrict__ poolV, unsigned* __restrict__ poolI,
        const float* __restrict__ v, const float* __restrict__ s_in,
        const float* __restrict__ hs,
        const float* __restrict__ W_ih, const float* __restrict__ b_ih,
        const float* __restrict__ W_hh, const float* __restrict__ b_hh,
        float* __restrict__ gi, float* __restrict__ gh) {
    const int t = threadIdx.x;
    if (blockIdx.x < NCOLLECT) {
        __shared__ unsigned lt[NBINS];
        __shared__ unsigned chunkS[64];
        __shared__ unsigned sB;
        #pragma unroll
        for (int i = t; i < NBINS; i += 256) lt[i] = tot[i];
        __syncthreads();
        if (t < 64) {
            unsigned s = 0;
            #pragma unroll 8
            for (int j = 0; j < 64; ++j) s += lt[t * 64 + ((j + t) & 63)];
            chunkS[t] = s;
        }
        __syncthreads();
        if (t == 0) {
            unsigned cum = 0; int c = 63;
            for (; c > 0; --c) {
                if (cum + chunkS[c] >= KSEL) break;
                cum += chunkS[c];
            }
            unsigned B = c * 64;
            for (int b = 63; b >= 0; --b) {
                unsigned hb = lt[c * 64 + b];
                if (cum + hb >= KSEL) { B = c * 64 + b; break; }
                cum += hb;
            }
            sB = B;
        }
        __syncthreads();
        const unsigned B = sB;
        const int lane = t & 63;
        const int pool = blockIdx.x & (NPOOL - 1);
        for (int i = blockIdx.x * 256 + t; i < N_HIST; i += NCOLLECT * 256) {
            float a = alpha[i];
            bool cand = (keyOf(a) >> 20) >= B;
            unsigned long long m = __ballot(cand);
            if (m) {
                int leader = __ffsll(m) - 1;
                unsigned base = 0;
                if (lane == leader) base = atomicAdd(&ctrl[8 + pool], (unsigned)__popcll(m));
                base = __shfl(base, leader);
                if (cand) {
                    unsigned pos = base + (unsigned)__popcll(m & ((1ull << lane) - 1ull));
                    if (pos < POOL_CAP) {
                        poolV[pool * POOL_CAP + pos] = a;
                        poolI[pool * POOL_CAP + pos] = (unsigned)i;
                    }
                }
            }
        }
    } else {
        // GRU matvec: one wave per output row o.
        const int o = ((int)blockIdx.x - NCOLLECT) * 4 + (t >> 6);
        const int l = t & 63;
        const float* wi = W_ih + (size_t)o * (TOPIC + 1);
        float pi = wi[l] * v[l] + wi[64 + l] * v[64 + l];
        if (l == 0) pi += wi[TOPIC] * s_in[0];
        const float2 wh = ((const float2*)(W_hh + (size_t)o * HID))[l];
        const float2 hh = ((const float2*)(hs + (size_t)(N_HIST - 1) * HID))[l];
        float ph = wh.x * hh.x + wh.y * hh.y;
        #pragma unroll
        for (int off = 32; off; off >>= 1) {
            pi += __shfl_xor(pi, off);
            ph += __shfl_xor(ph, off);
        }
        if (l == 0) {
            gi[o] = pi + b_ih[o];
            gh[o] = ph + b_hh[o];
        }
    }
}

// Kernel 4: rank-based top-50 + decay + softmax + attn + score + GRU gates.
__global__ __launch_bounds__(512) void final_kernel(
        const float* __restrict__ v, const float* __restrict__ t_in,
        const float* __restrict__ hs, const float* __restrict__ ts,
        const float* __restrict__ W_score, const float* __restrict__ b_score,
        const unsigned* __restrict__ ctrl,
        const float* __restrict__ poolV, const unsigned* __restrict__ poolI,
        const float* __restrict__ giW, const float* __restrict__ ghW,
        float* __restrict__ out) {
    __shared__ float candV[NPOOL * POOL_CAP];
    __shared__ unsigned candI[NPOOL * POOL_CAP];
    __shared__ unsigned pc[NPOOL];
    __shared__ int off[NPOOL + 1];
    __shared__ float selV[KSEL];
    __shared__ unsigned selI[KSEL];
    __shared__ float selD[KSEL];
    __shared__ float wtmp[KSEL];
    __shared__ float w[KSEL];
    __shared__ float xv[TOPIC];
    __shared__ float h0[HID];
    __shared__ float attnP[4][HID];
    __shared__ float red[HID];

    const int t = threadIdx.x;
    const int wv = t >> 6, l = t & 63;

    if (t < NPOOL) pc[t] = min(ctrl[8 + t], (unsigned)POOL_CAP);
    if (t >= 128 && t < 256) xv[t - 128] = v[t - 128];
    if (t >= 256 && t < 256 + HID) h0[t - 256] = hs[(size_t)(N_HIST - 1) * HID + (t - 256)];
    __syncthreads();
    if (t == 0) {
        int o = 0;
        for (int p = 0; p < NPOOL; ++p) { off[p] = o; o += (int)pc[p]; }
        off[NPOOL] = o;
    }
    __syncthreads();

    for (int p = wv; p < NPOOL; p += 8) {
        const int cnt = off[p + 1] - off[p];
        for (int i = l; i < cnt; i += 64) {
            candV[off[p] + i] = poolV[p * POOL_CAP + i];
            candI[off[p] + i] = poolI[p * POOL_CAP + i];
        }
    }
    __syncthreads();

    const int Scand = off[NPOOL];
    const int S = Scand < KSEL ? Scand : KSEL;

    // rank-based selection: one pass, broadcast LDS reads, no shuffles
    for (int c = t; c < Scand; c += 512) {
        const float mv = candV[c];
        const unsigned mi = candI[c];
        int r = 0;
        for (int j = 0; j < Scand; ++j) {
            const float vj = candV[j];
            const unsigned ij = candI[j];
            r += (int)((vj > mv) | ((vj == mv) & (ij < mi)));
        }
        if (r < KSEL) { selV[r] = mv; selI[r] = mi; }
    }
    __syncthreads();

    // decay + softmax on wave 0
    if (wv == 0) {
        const float tt = t_in[0];
        float dv = NEG_INF;
        if (l < S) {
            dv = selV[l] * expf((tt - ts[selI[l]]) * LOG_DECAY);
            selD[l] = dv;
        }
        __threadfence_block();
        float m = NEG_INF;
        for (int k = 0; k < S; ++k) m = fmaxf(m, selD[k]);
        float e = (l < S) ? expf(dv - m) : 0.f;
        if (l < S) wtmp[l] = e;
        __threadfence_block();
        float sum = 0.f;
        for (int k = 0; k < S; ++k) sum += wtmp[k];
        if (l < S) w[l] = e / sum;
    }
    __syncthreads();

    // attn partials: 4-way split over k, coalesced hs rows
    {
        const int g = t >> 7, col = t & 127;
        float acc = 0.f;
        for (int k = g; k < S; k += 4)
            acc += w[k] * hs[(size_t)selI[k] * HID + col];
        attnP[g][col] = acc;
    }
    __syncthreads();

    if (t < HID) {
        const float ah = attnP[0][t] + attnP[1][t] + attnP[2][t] + attnP[3][t];
        red[t] = xv[t] * W_score[t] + ah * W_score[HID + t];
        const float r = 1.f / (1.f + expf(-(giW[t] + ghW[t])));
        const float z = 1.f / (1.f + expf(-(giW[HID + t] + ghW[HID + t])));
        const float n = tanhf(giW[2 * HID + t] + r * ghW[2 * HID + t]);
        out[1 + t] = (1.f - z) * n + z * h0[t];
    }
    __syncthreads();

    if (t < 64) {
        float sv = red[t] + red[64 + t];
        #pragma unroll
        for (int offx = 32; offx; offx >>= 1) sv += __shfl_xor(sv, offx);
        if (t == 0) out[0] = sv + b_score[0];
    }
}

extern "C" void kernel_launch(void* const* d_in, const int* in_sizes, int n_in,
                              void* d_out, int out_size, void* d_ws, size_t ws_size,
                              hipStream_t stream) {
    const float* v       = (const float*)d_in[0];
    const float* s_in    = (const float*)d_in[1];
    const float* t_in    = (const float*)d_in[2];
    const float* vs      = (const float*)d_in[3];
    const float* hs      = (const float*)d_in[4];
    const float* ts      = (const float*)d_in[5];
    const float* W_ih    = (const float*)d_in[6];
    const float* b_ih    = (const float*)d_in[7];
    const float* W_hh    = (const float*)d_in[8];
    const float* b_hh    = (const float*)d_in[9];
    const float* W_score = (const float*)d_in[10];
    const float* b_score = (const float*)d_in[11];
    float* out = (float*)d_out;

    unsigned* ws   = (unsigned*)d_ws;
    unsigned* ctrl = ws + WS_CTRL;
    unsigned* tot  = ws + WS_TOT;
    float*    alpha = (float*)(ws + WS_ALPHA);
    float*    poolV = (float*)(ws + WS_POOLV);
    unsigned* poolI = ws + WS_POOLI;
    float*    giW   = (float*)(ws + WS_GI);
    float*    ghW   = (float*)(ws + WS_GH);

    alpha_kernel<<<3125, 256, 0, stream>>>(vs, v, alpha, ws);
    hist_kernel<<<NHISTBLK, 256, 0, stream>>>(alpha, tot);
    mid_kernel<<<NCOLLECT + 96, 256, 0, stream>>>(alpha, tot, ctrl, poolV, poolI,
                                                  v, s_in, hs, W_ih, b_ih, W_hh, b_hh,
                                                  giW, ghW);
    final_kernel<<<1, 512, 0, stream>>>(v, t_in, hs, ts, W_score, b_score,
                                        ctrl, poolV, poolI, giW, ghW, out);
}

// Round 6
// 46.235 us; speedup vs baseline: 4.8576x; 1.0759x over previous
//
#include <hip/hip_runtime.h>
#include <math.h>

#define N_HIST 200000
#define TOPIC 128
#define HID 128
#define KSEL 50
#define NBINS 4096           // 12-bit order-key bins (sign+8exp+3mant)
#define NHISTBLK 64
#define NCOLLECT 128
#define NPOOL 32
#define POOL_CAP 256
#define NEG_INF (-3.402823466e38f)
// log(float32(1.0 - 1e-7)) = log(0.99999988079071045)
#define LOG_DECAY (-1.1920930e-07f)

// ws layout (4-byte words): ctrl+tot zeroed by alpha_kernel's first blocks.
enum { WS_CTRL  = 0,                       // 64: [8..39] pool counts
       WS_TOT   = 64,                      // 4096
       WS_ZEND  = WS_TOT + NBINS,          // 4160 = zero region end
       WS_ALPHA = WS_ZEND,                 // 200000
       WS_POOLV = WS_ALPHA + N_HIST,       // 8192
       WS_POOLI = WS_POOLV + NPOOL * POOL_CAP,  // 8192
       WS_GI    = WS_POOLI + NPOOL * POOL_CAP,  // 384
       WS_GH    = WS_GI + 3 * HID };            // 384

__device__ __forceinline__ unsigned keyOf(float f) {
    unsigned u = __float_as_uint(f);
    return (u & 0x80000000u) ? ~u : (u | 0x80000000u);
}

// Kernel 1: alpha[i] = dot(vs[i], v); first 17 blocks also zero ctrl+tot.
__global__ __launch_bounds__(256) void alpha_kernel(
        const float* __restrict__ vs, const float* __restrict__ v,
        float* __restrict__ alpha, unsigned* __restrict__ wsbase) {
    const int zi = blockIdx.x * 256 + threadIdx.x;
    if (zi < WS_ZEND) wsbase[zi] = 0;
    const int lane = threadIdx.x & 63;
    const int wave = (blockIdx.x * blockDim.x + threadIdx.x) >> 6;
    const int half = lane >> 5;
    const int c = lane & 31;
    const int base = wave * 16 + half * 8;
    const float4 vv = ((const float4*)v)[c];
    float4 a[8];
    #pragma unroll
    for (int r = 0; r < 8; ++r)
        a[r] = ((const float4*)vs)[(size_t)(base + r) * 32 + c];
    float s[8];
    #pragma unroll
    for (int r = 0; r < 8; ++r)
        s[r] = a[r].x * vv.x + a[r].y * vv.y + a[r].z * vv.z + a[r].w * vv.w;
    #pragma unroll
    for (int off = 16; off; off >>= 1) {
        #pragma unroll
        for (int r = 0; r < 8; ++r) s[r] += __shfl_xor(s[r], off);
    }
    if (c == 0) {
        float4* dst = (float4*)(alpha + base);
        dst[0] = make_float4(s[0], s[1], s[2], s[3]);
        dst[1] = make_float4(s[4], s[5], s[6], s[7]);
    }
}

// Kernel 2: 12-bit histogram. Per-block packed 2x16-bit LDS bins, then one
// global atomic per nonzero bin per block (uncontended, ~64 max per address).
__global__ __launch_bounds__(256) void hist_kernel(
        const float* __restrict__ alpha, unsigned* __restrict__ tot) {
    __shared__ unsigned h[NBINS / 2];
    const int t = threadIdx.x;
    #pragma unroll
    for (int i = t; i < NBINS / 2; i += 256) h[i] = 0;
    __syncthreads();
    for (int i = blockIdx.x * 256 + t; i < N_HIST; i += NHISTBLK * 256) {
        unsigned b = keyOf(alpha[i]) >> 20;
        atomicAdd(&h[b >> 1], (b & 1u) ? 65536u : 1u);
    }
    __syncthreads();
    #pragma unroll
    for (int wd = t; wd < NBINS / 2; wd += 256) {
        unsigned pk = h[wd];
        unsigned lo = pk & 0xFFFFu, hi = pk >> 16;
        if (lo) atomicAdd(&tot[2 * wd], lo);
        if (hi) atomicAdd(&tot[2 * wd + 1], hi);
    }
}

// Kernel 3 (fused): blocks 0..127 collect candidates (each block redundantly
// recomputes threshold bin B from tot); blocks 128..223 do the GRU matvecs.
__global__ __launch_bounds__(256) void mid_kernel(
        const float* __restrict__ alpha, const unsigned* __restrict__ tot,
        unsigned* __restrict__ ctrl,
        float* __restrict__ poolV, unsigned* __restrict__ poolI,
        const float* __restrict__ v, const float* __restrict__ s_in,
        const float* __restrict__ hs,
        const float* __restrict__ W_ih, const float* __restrict__ b_ih,
        const float* __restrict__ W_hh, const float* __restrict__ b_hh,
        float* __restrict__ gi, float* __restrict__ gh) {
    const int t = threadIdx.x;
    if (blockIdx.x < NCOLLECT) {
        __shared__ unsigned lt[NBINS];
        __shared__ unsigned chunkS[64];
        __shared__ unsigned sB;
        #pragma unroll
        for (int i = t; i < NBINS; i += 256) lt[i] = tot[i];
        __syncthreads();
        if (t < 64) {
            unsigned s = 0;
            #pragma unroll 8
            for (int j = 0; j < 64; ++j) s += lt[t * 64 + ((j + t) & 63)];
            chunkS[t] = s;
        }
        __syncthreads();
        if (t == 0) {
            unsigned cum = 0; int c = 63;
            for (; c > 0; --c) {
                if (cum + chunkS[c] >= KSEL) break;
                cum += chunkS[c];
            }
            unsigned B = c * 64;
            for (int b = 63; b >= 0; --b) {
                unsigned hb = lt[c * 64 + b];
                if (cum + hb >= KSEL) { B = c * 64 + b; break; }
                cum += hb;
            }
            sB = B;
        }
        __syncthreads();
        const unsigned B = sB;
        const int lane = t & 63;
        const int pool = blockIdx.x & (NPOOL - 1);
        for (int i = blockIdx.x * 256 + t; i < N_HIST; i += NCOLLECT * 256) {
            float a = alpha[i];
            bool cand = (keyOf(a) >> 20) >= B;
            unsigned long long m = __ballot(cand);
            if (m) {
                int leader = __ffsll(m) - 1;
                unsigned base = 0;
                if (lane == leader) base = atomicAdd(&ctrl[8 + pool], (unsigned)__popcll(m));
                base = __shfl(base, leader);
                if (cand) {
                    unsigned pos = base + (unsigned)__popcll(m & ((1ull << lane) - 1ull));
                    if (pos < POOL_CAP) {
                        poolV[pool * POOL_CAP + pos] = a;
                        poolI[pool * POOL_CAP + pos] = (unsigned)i;
                    }
                }
            }
        }
    } else {
        // GRU matvec: one wave per output row o.
        const int o = ((int)blockIdx.x - NCOLLECT) * 4 + (t >> 6);
        const int l = t & 63;
        const float* wi = W_ih + (size_t)o * (TOPIC + 1);
        float pi = wi[l] * v[l] + wi[64 + l] * v[64 + l];
        if (l == 0) pi += wi[TOPIC] * s_in[0];
        const float2 wh = ((const float2*)(W_hh + (size_t)o * HID))[l];
        const float2 hh = ((const float2*)(hs + (size_t)(N_HIST - 1) * HID))[l];
        float ph = wh.x * hh.x + wh.y * hh.y;
        #pragma unroll
        for (int off = 32; off; off >>= 1) {
            pi += __shfl_xor(pi, off);
            ph += __shfl_xor(ph, off);
        }
        if (l == 0) {
            gi[o] = pi + b_ih[o];
            gh[o] = ph + b_hh[o];
        }
    }
}

// Kernel 4: fully wave-parallel finale. Prefix-scan via shfl_up, ballot-rank
// top-50, shuffle-reduce softmax, 8-way float2 attn gather, score + GRU gates.
__global__ __launch_bounds__(512) void final_kernel(
        const float* __restrict__ v, const float* __restrict__ t_in,
        const float* __restrict__ hs, const float* __restrict__ ts,
        const float* __restrict__ W_score, const float* __restrict__ b_score,
        const unsigned* __restrict__ ctrl,
        const float* __restrict__ poolV, const unsigned* __restrict__ poolI,
        const float* __restrict__ giW, const float* __restrict__ ghW,
        float* __restrict__ out) {
    __shared__ float candV[NPOOL * POOL_CAP];
    __shared__ unsigned candI[NPOOL * POOL_CAP];
    __shared__ int off[NPOOL + 1];
    __shared__ float selV[KSEL];
    __shared__ unsigned selI[KSEL];
    __shared__ float w[KSEL];
    __shared__ float xv[TOPIC];
    __shared__ float h0[HID];
    __shared__ float attnP[8][130];
    __shared__ float red[HID];

    const int t = threadIdx.x;
    const int wv = t >> 6, l = t & 63;

    // Phase 0: wave0 prefix-scans pool counts; other waves stage xv/h0.
    if (wv == 0) {
        unsigned pcv = (l < NPOOL) ? min(ctrl[8 + l], (unsigned)POOL_CAP) : 0u;
        int x = (int)pcv;
        #pragma unroll
        for (int d = 1; d < 32; d <<= 1) {
            int y = __shfl_up(x, d);
            if (l >= d) x += y;
        }
        if (l < NPOOL) off[l] = x - (int)pcv;
        if (l == NPOOL - 1) off[NPOOL] = x;
    } else if (t >= 64 && t < 192) {
        xv[t - 64] = v[t - 64];
    } else if (t >= 192 && t < 320) {
        h0[t - 192] = hs[(size_t)(N_HIST - 1) * HID + (t - 192)];
    }
    __syncthreads();

    const int Scand = off[NPOOL];
    const int S = Scand < KSEL ? Scand : KSEL;

    // Phase 1: compact pools -> cand arrays, 16 threads per pool.
    {
        const int p = t >> 4, i0 = t & 15;
        const int base = off[p], cnt = off[p + 1] - base;
        for (int i = i0; i < cnt; i += 16) {
            candV[base + i] = poolV[p * POOL_CAP + i];
            candI[base + i] = poolI[p * POOL_CAP + i];
        }
    }
    __syncthreads();

    // Phase 2: ballot-rank selection; wave wv handles candidates wv, wv+8, ...
    for (int c = wv; c < Scand; c += 8) {
        const float mv = candV[c];
        const unsigned mi = candI[c];
        int cnt = 0;
        for (int j0 = 0; j0 < Scand; j0 += 64) {
            const int j = j0 + l;
            bool gt = false;
            if (j < Scand) {
                const float vj = candV[j];
                const unsigned ij = candI[j];
                gt = (vj > mv) || ((vj == mv) && (ij < mi));
            }
            cnt += (int)__popcll(__ballot(gt));
        }
        if (l == 0 && cnt < KSEL) { selV[cnt] = mv; selI[cnt] = mi; }
    }
    __syncthreads();

    // Phase 3: decay + softmax on wave 0, shuffle reductions.
    if (wv == 0) {
        const float tt = t_in[0];
        float dv = NEG_INF;
        if (l < S) dv = selV[l] * expf((tt - ts[selI[l]]) * LOG_DECAY);
        float m = dv;
        #pragma unroll
        for (int o = 32; o; o >>= 1) m = fmaxf(m, __shfl_xor(m, o));
        float e = (l < S) ? expf(dv - m) : 0.f;
        float sum = e;
        #pragma unroll
        for (int o = 32; o; o >>= 1) sum += __shfl_xor(sum, o);
        if (l < S) w[l] = e / sum;
    }
    __syncthreads();

    // Phase 4: attn partials; wave wv takes k = wv, wv+8, ...; lane = 2 cols.
    {
        float2 acc = make_float2(0.f, 0.f);
        for (int k = wv; k < S; k += 8) {
            const float wk = w[k];
            const float2 hv = ((const float2*)(hs + (size_t)selI[k] * HID))[l];
            acc.x += wk * hv.x; acc.y += wk * hv.y;
        }
        attnP[wv][2 * l]     = acc.x;
        attnP[wv][2 * l + 1] = acc.y;
    }
    __syncthreads();

    // Phase 5: score partial + GRU gates.
    if (t < HID) {
        float ah = 0.f;
        #pragma unroll
        for (int g = 0; g < 8; ++g) ah += attnP[g][t];
        red[t] = xv[t] * W_score[t] + ah * W_score[HID + t];
        const float r = 1.f / (1.f + expf(-(giW[t] + ghW[t])));
        const float z = 1.f / (1.f + expf(-(giW[HID + t] + ghW[HID + t])));
        const float n = tanhf(giW[2 * HID + t] + r * ghW[2 * HID + t]);
        out[1 + t] = (1.f - z) * n + z * h0[t];
    }
    __syncthreads();

    if (t < 64) {
        float sv = red[t] + red[64 + t];
        #pragma unroll
        for (int o = 32; o; o >>= 1) sv += __shfl_xor(sv, o);
        if (t == 0) out[0] = sv + b_score[0];
    }
}

extern "C" void kernel_launch(void* const* d_in, const int* in_sizes, int n_in,
                              void* d_out, int out_size, void* d_ws, size_t ws_size,
                              hipStream_t stream) {
    const float* v       = (const float*)d_in[0];
    const float* s_in    = (const float*)d_in[1];
    const float* t_in    = (const float*)d_in[2];
    const float* vs      = (const float*)d_in[3];
    const float* hs      = (const float*)d_in[4];
    const float* ts      = (const float*)d_in[5];
    const float* W_ih    = (const float*)d_in[6];
    const float* b_ih    = (const float*)d_in[7];
    const float* W_hh    = (const float*)d_in[8];
    const float* b_hh    = (const float*)d_in[9];
    const float* W_score = (const float*)d_in[10];
    const float* b_score = (const float*)d_in[11];
    float* out = (float*)d_out;

    unsigned* ws   = (unsigned*)d_ws;
    unsigned* ctrl = ws + WS_CTRL;
    unsigned* tot  = ws + WS_TOT;
    float*    alpha = (float*)(ws + WS_ALPHA);
    float*    poolV = (float*)(ws + WS_POOLV);
    unsigned* poolI = ws + WS_POOLI;
    float*    giW   = (float*)(ws + WS_GI);
    float*    ghW   = (float*)(ws + WS_GH);

    alpha_kernel<<<3125, 256, 0, stream>>>(vs, v, alpha, ws);
    hist_kernel<<<NHISTBLK, 256, 0, stream>>>(alpha, tot);
    mid_kernel<<<NCOLLECT + 96, 256, 0, stream>>>(alpha, tot, ctrl, poolV, poolI,
                                                  v, s_in, hs, W_ih, b_ih, W_hh, b_hh,
                                                  giW, ghW);
    final_kernel<<<1, 512, 0, stream>>>(v, t_in, hs, ts, W_score, b_score,
                                        ctrl, poolV, poolI, giW, ghW, out);
}